// Round 10
// baseline (7396.977 us; speedup 1.0000x reference)
//
#include <hip/hip_runtime.h>
#include <cstdint>
#include <cstddef>

typedef unsigned short ushort_t;
typedef unsigned int uint_t;
typedef __attribute__((ext_vector_type(8))) __bf16 bf16x8;
typedef __attribute__((ext_vector_type(4))) float f32x4;
typedef __attribute__((ext_vector_type(2))) unsigned int u32x2;

static constexpr int T_STEPS = 512;
static constexpr int BATCH   = 256;
static constexpr int OBS_D   = 64;
static constexpr int ACT_D   = 8;
static constexpr int HID_D   = 1024;
static constexpr int CELL_D  = 512;
static constexpr int GATE_D  = 4 * CELL_D;   // 2048
static constexpr int SCAN_BLOCKS = 32;       // each owns 64 P-cols = 16 cells

__device__ __forceinline__ float bf2f(ushort_t s) {
    uint_t u = ((uint_t)s) << 16;
    float f;
    __builtin_memcpy(&f, &u, 4);
    return f;
}
__device__ __forceinline__ ushort_t f2bf(float x) {
    uint_t u;
    __builtin_memcpy(&u, &x, 4);
    u += 0x7fffu + ((u >> 16) & 1u);   // RNE
    return (ushort_t)(u >> 16);
}

// ---- fast transcendentals (v_exp_f32 / v_rcp_f32; exact at saturation) ----
__device__ __forceinline__ float sigmoid_fast(float x) {
    return __builtin_amdgcn_rcpf(1.f + __expf(-x));
}
__device__ __forceinline__ float tanh_fast(float x) {
    const float e = __expf(-2.f * fabsf(x));          // in [0,1]
    const float r = (1.f - e) * __builtin_amdgcn_rcpf(1.f + e);
    return copysignf(r, x);
}

// ---- f32 -> bf16 bulk convert (8/thread; n multiple of 2048) ----
__global__ __launch_bounds__(256)
void cvt_f32_bf16(const float* __restrict__ in, ushort_t* __restrict__ out)
{
    const size_t i = ((size_t)blockIdx.x * 256 + threadIdx.x) * 8;
    const float4 v0 = *(const float4*)(in + i);
    const float4 v1 = *(const float4*)(in + i + 4);
    uint4 p;
    p.x = (uint_t)f2bf(v0.x) | ((uint_t)f2bf(v0.y) << 16);
    p.y = (uint_t)f2bf(v0.z) | ((uint_t)f2bf(v0.w) << 16);
    p.z = (uint_t)f2bf(v1.x) | ((uint_t)f2bf(v1.y) << 16);
    p.w = (uint_t)f2bf(v1.z) | ((uint_t)f2bf(v1.w) << 16);
    *(uint4*)(out + i) = p;
}

// Gate-major [4*C][K] f32 -> cell-major permuted bf16: Wp[P=c*4+g][k]
// (used for W_ih -> gx_p layout: gates of cell c at gx[c*4+g])
__global__ __launch_bounds__(256)
void permute_gate_rows(const float* __restrict__ W, ushort_t* __restrict__ Wp, int K)
{
    const int P = blockIdx.x;               // 0..2047
    const int c = P >> 2, g = P & 3;
    const float* src = W + (size_t)(g * CELL_D + c) * K;
    ushort_t* dst = Wp + (size_t)P * K;
    for (int k = threadIdx.x; k < K; k += 256) dst[k] = f2bf(src[k]);
}

// W_hh permute for the scan's lane->cell mapping:
// global row blk*64 + t*16 + q*4 + r  <-  W_hh[gate r][cell blk*16 + q*4 + t]
// so lane (q,s) tile t reg r = gate r of cell blk*16+q*4+t (4 CONTIGUOUS cells/lane).
__global__ __launch_bounds__(256)
void permute_whh_rows(const float* __restrict__ W, ushort_t* __restrict__ Wp, int K)
{
    const int P = blockIdx.x;               // 0..2047
    const int blk = P >> 6, rl = P & 63;
    const int t = rl >> 4, qq = (rl >> 2) & 3, r = rl & 3;
    const float* src = W + (size_t)(r * CELL_D + blk * 16 + qq * 4 + t) * K;
    ushort_t* dst = Wp + (size_t)P * K;
    for (int k = threadIdx.x; k < K; k += 256) dst[k] = f2bf(src[k]);
}

__global__ __launch_bounds__(256)
void permute_bias(const float* __restrict__ b, float* __restrict__ bp)
{
    const int P = blockIdx.x * 256 + threadIdx.x;   // grid 8
    bp[P] = b[(P & 3) * CELL_D + (P >> 2)];
}

// ---- MFMA bf16 GEMM: C[m][n] = sum_k A[m][k]*B[n][k] + bias[n] ----
// 128x128 tile, BK=32, 4 waves, 4x4 16x16x32 frags/wave.
// OUT_MODE: 0 = f32, 1 = bf16+ReLU, 2 = bf16 linear
template<int OUT_MODE>
__global__ __launch_bounds__(256)
void gemm_mfma_nt(const ushort_t* __restrict__ A, const ushort_t* __restrict__ B,
                  const float* __restrict__ bias, void* __restrict__ out_,
                  int N, int K)
{
    __shared__ __align__(16) ushort_t As[128 * 32];
    __shared__ __align__(16) ushort_t Bs[128 * 32];
    const int tid  = threadIdx.x;
    const int lane = tid & 63;
    const int wid  = tid >> 6;
    const int wr   = (wid >> 1) * 64;
    const int wc   = (wid & 1) * 64;
    const int m0 = blockIdx.y * 128;
    const int n0 = blockIdx.x * 128;

    const int srow = tid >> 2;
    const int sv   = tid & 3;
    const int fr   = lane & 15;
    const int fo   = lane >> 4;

    f32x4 acc[4][4];
#pragma unroll
    for (int i = 0; i < 4; ++i)
#pragma unroll
        for (int j = 0; j < 4; ++j) acc[i][j] = (f32x4){0.f, 0.f, 0.f, 0.f};

    const ushort_t* Apt = A + (size_t)(m0 + srow) * K + sv * 8;
    const ushort_t* Bpt = B + (size_t)(n0 + srow) * K + sv * 8;
    uint4* As4 = (uint4*)As;
    uint4* Bs4 = (uint4*)Bs;
    const bf16x8* Af = (const bf16x8*)As;
    const bf16x8* Bf = (const bf16x8*)Bs;

    for (int k0 = 0; k0 < K; k0 += 32) {
        const uint4 a0 = *(const uint4*)(Apt + k0);
        const uint4 a1 = *(const uint4*)(Apt + (size_t)64 * K + k0);
        const uint4 b0 = *(const uint4*)(Bpt + k0);
        const uint4 b1 = *(const uint4*)(Bpt + (size_t)64 * K + k0);
        __syncthreads();
        As4[srow * 4 + sv]        = a0;
        As4[(64 + srow) * 4 + sv] = a1;
        Bs4[srow * 4 + sv]        = b0;
        Bs4[(64 + srow) * 4 + sv] = b1;
        __syncthreads();

        bf16x8 av[4], bv[4];
#pragma unroll
        for (int m = 0; m < 4; ++m) av[m] = Af[(wr + m * 16 + fr) * 4 + fo];
#pragma unroll
        for (int n = 0; n < 4; ++n) bv[n] = Bf[(wc + n * 16 + fr) * 4 + fo];
#pragma unroll
        for (int m = 0; m < 4; ++m)
#pragma unroll
            for (int n = 0; n < 4; ++n)
                acc[m][n] = __builtin_amdgcn_mfma_f32_16x16x32_bf16(
                    av[m], bv[n], acc[m][n], 0, 0, 0);
    }

#pragma unroll
    for (int n = 0; n < 4; ++n) {
        const int col = n0 + wc + n * 16 + fr;
        const float bvv = bias[col];
#pragma unroll
        for (int m = 0; m < 4; ++m) {
            const int row0 = m0 + wr + m * 16 + fo * 4;
#pragma unroll
            for (int r = 0; r < 4; ++r) {
                const float v = acc[m][n][r] + bvv;
                if constexpr (OUT_MODE == 1)
                    ((ushort_t*)out_)[(size_t)(row0 + r) * N + col] = f2bf(fmaxf(v, 0.f));
                else if constexpr (OUT_MODE == 2)
                    ((ushort_t*)out_)[(size_t)(row0 + r) * N + col] = f2bf(v);
                else
                    ((float*)out_)[(size_t)(row0 + r) * N + col] = v;
            }
        }
    }
}

// ---- h-read pipeline helpers (quarter = 4 K-steps, 8x16B loads) ----
__device__ __forceinline__ void loadq(uint4 (&d0)[4], uint4 (&d1)[4],
                                      const ushort_t* hr0, const ushort_t* hr1,
                                      int base)
{
#pragma unroll
    for (int j = 0; j < 4; ++j) {
        d0[j] = *(const uint4*)(hr0 + (base + j) * 32);
        d1[j] = *(const uint4*)(hr1 + (base + j) * 32);
    }
}

// Pt 0,1 A-operands from step-invariant registers (wreg), Pt 2,3 from LDS.
// base is a compile-time literal -> wreg indices are static (stay in VGPRs).
__device__ __forceinline__ void compq(const uint4 (&d0)[4], const uint4 (&d1)[4],
                                      const bf16x8 (&wreg)[2][16],
                                      const char* wsrow, int q16, int xmask,
                                      int base, f32x4 (&acc)[4][2])
{
#pragma unroll
    for (int j = 0; j < 4; ++j) {
        bf16x8 hv0, hv1;
        __builtin_memcpy(&hv0, &d0[j], 16);
        __builtin_memcpy(&hv1, &d1[j], 16);
        const int ks = base + j;
        const int koff = (ks * 64 + q16) ^ xmask;
        acc[0][0] = __builtin_amdgcn_mfma_f32_16x16x32_bf16(wreg[0][ks], hv0, acc[0][0], 0, 0, 0);
        acc[0][1] = __builtin_amdgcn_mfma_f32_16x16x32_bf16(wreg[0][ks], hv1, acc[0][1], 0, 0, 0);
        acc[1][0] = __builtin_amdgcn_mfma_f32_16x16x32_bf16(wreg[1][ks], hv0, acc[1][0], 0, 0, 0);
        acc[1][1] = __builtin_amdgcn_mfma_f32_16x16x32_bf16(wreg[1][ks], hv1, acc[1][1], 0, 0, 0);
#pragma unroll
        for (int Pt = 2; Pt < 4; ++Pt) {
            const bf16x8 av = *(const bf16x8*)(wsrow + (Pt - 2) * 16 * 1024 + koff);
            acc[Pt][0] = __builtin_amdgcn_mfma_f32_16x16x32_bf16(av, hv0, acc[Pt][0], 0, 0, 0);
            acc[Pt][1] = __builtin_amdgcn_mfma_f32_16x16x32_bf16(av, hv1, acc[Pt][1], 0, 0, 0);
        }
    }
}

// ---- persistent LSTM scan, 32 blocks x 512 threads, PER-WAVE CHAINS ----
// Round-9 structure + ONE change: HALF of W hoisted to registers.
// The A-operand fragments are IDENTICAL across the 8 waves (wsrow depends on
// lane only), and W is step-invariant — yet every wave re-read the full 64KB
// slice from LDS every step: 8x64 ds_read_b128 ~2.6us + 0.85us conflicts =
// ~3.4us/CU-step, the largest pipe. Now Pt 0,1 fragments (32 x bf16x8 = 128
// VGPR) are loaded from global ONCE; LDS keeps only rows 32..63 (32KB) for
// Pt 2,3. Per-step LDS reads and conflicts halve. VGPR ~92->~220 (2
// waves/SIMD preserved). Same operand values, same MFMA order -> bit-identical.
__global__ __launch_bounds__(512)
void lstm_scan(const ushort_t* __restrict__ gx_p,   // [Tc*256][2048] bf16 (P-cols)
               const ushort_t* __restrict__ Whh_p,  // [2048][512] bf16 (scan permute)
               const float* __restrict__ b_hh,      // [2048] f32 gate-major
               const float* __restrict__ masks_c,   // [Tc*256]
               const ushort_t* h_init,              // [256][512] bf16
               float* __restrict__ c_state,         // [256][512] f32 in/out
               ushort_t* hid,                       // [Tc][256][512] bf16 out
               float* __restrict__ hT_f32,
               int Tc, int is_last,
               uint_t* __restrict__ bar)            // flags[8][32], 128B/chain
{
    __shared__ __align__(16) ushort_t Ws[32 * 512];   // 32 KiB: rows 32..63 only

    const int tid  = threadIdx.x;
    const int lane = tid & 63;
    const int w    = tid >> 6;      // wave/chain 0..7 -> batch rows [w*32,+32)
    const int q    = lane >> 4;     // 0..3
    const int s    = lane & 15;
    const int blk  = blockIdx.x;
    const int xmask = (s & 7) << 4; // LDS XOR swizzle for A-frag reads
    const int q16  = q * 16;
    const int cell0 = blk * 16 + q * 4;   // lane's 4 contiguous cells

    // ---- W rows 32..63 -> LDS (swizzled); local row = global row - 32 ----
    for (int idx = tid; idx < 32 * 64; idx += 512) {
        const int row = idx >> 6;          // local 0..31
        const int c16 = idx & 63;          // 16B chunk
        const uint4 v = *(const uint4*)(Whh_p + (size_t)(blk * 64 + 32 + row) * CELL_D + c16 * 8);
        *(uint4*)((char*)Ws + row * 1024 + ((c16 * 16) ^ ((row & 7) << 4))) = v;
    }

    // ---- W rows 0..31 (Pt 0,1) -> registers, step-invariant ----
    bf16x8 wreg[2][16];
#pragma unroll
    for (int Pt = 0; Pt < 2; ++Pt)
#pragma unroll
        for (int ks = 0; ks < 16; ++ks)
            wreg[Pt][ks] = *(const bf16x8*)(Whh_p
                + (size_t)(blk * 64 + Pt * 16 + s) * CELL_D + ks * 32 + q * 8);

    const int b0 = w * 32 + s;        // nfl=0 batch row
    const int b1 = b0 + 16;           // nfl=1

    // ---- per-lane state (float4: cells contiguous) ----
    float creg[4][2];
    {
        const float4 c40 = *(const float4*)(c_state + (size_t)b0 * CELL_D + cell0);
        const float4 c41 = *(const float4*)(c_state + (size_t)b1 * CELL_D + cell0);
        creg[0][0] = c40.x; creg[1][0] = c40.y; creg[2][0] = c40.z; creg[3][0] = c40.w;
        creg[0][1] = c41.x; creg[1][1] = c41.y; creg[2][1] = c41.z; creg[3][1] = c41.w;
    }
    float bh[4][4];
#pragma unroll
    for (int r = 0; r < 4; ++r) {
        const float4 b4 = *(const float4*)(b_hh + r * CELL_D + cell0);
        bh[0][r] = b4.x; bh[1][r] = b4.y; bh[2][r] = b4.z; bh[3][r] = b4.w;
    }

    // ---- per-chain prefetch (gx + masks for the CURRENT step) ----
    float mv0, mv1;
    uint2 gxv[4][2];
    auto prefetch_step = [&](int TL) {
        const ushort_t* g0 = gx_p + ((size_t)TL * BATCH + b0) * GATE_D + blk * 64 + q * 16;
        const ushort_t* g1 = g0 + (size_t)16 * GATE_D;
#pragma unroll
        for (int t = 0; t < 4; ++t) {
            gxv[t][0] = *(const uint2*)(g0 + t * 4);
            gxv[t][1] = *(const uint2*)(g1 + t * 4);
        }
        mv0 = masks_c[(size_t)TL * BATCH + b0];
        mv1 = masks_c[(size_t)TL * BATCH + b1];
    };
    prefetch_step(0);

    const char* wsrow = (const char*)Ws + s * 1024;
    __syncthreads();                  // Ws staging complete (only sync)

    // ---- phase stagger: chain w delays ~w*0.8us once (kept from round 9) ----
    for (int i = 0; i < w * 4; ++i) __builtin_amdgcn_s_sleep(8);

    for (int tl = 0; tl < Tc; ++tl) {
        const ushort_t* hp = (tl == 0) ? h_init
                                       : hid + (size_t)(tl - 1) * BATCH * CELL_D;
        const ushort_t* hr0 = hp + (size_t)b0 * CELL_D + q * 8;
        const ushort_t* hr1 = hp + (size_t)b1 * CELL_D + q * 8;

        f32x4 acc[4][2];
#pragma unroll
        for (int t = 0; t < 4; ++t) {
            acc[t][0] = (f32x4){0.f, 0.f, 0.f, 0.f};
            acc[t][1] = (f32x4){0.f, 0.f, 0.f, 0.f};
        }

        // ---- pipelined h-read + MFMA: quarters, 2 in flight ----
        uint4 A0[4], A1[4], B0[4], B1[4];
        loadq(A0, A1, hr0, hr1, 0);
        loadq(B0, B1, hr0, hr1, 4);
        compq(A0, A1, wreg, wsrow, q16, xmask, 0, acc);
        loadq(A0, A1, hr0, hr1, 8);
        compq(B0, B1, wreg, wsrow, q16, xmask, 4, acc);
        loadq(B0, B1, hr0, hr1, 12);
        compq(A0, A1, wreg, wsrow, q16, xmask, 8, acc);
        compq(B0, B1, wreg, wsrow, q16, xmask, 12, acc);

        // ---- cell update (mask post-MFMA; exact for keep in {0,1}) ----
        const float keep0 = (mv0 > 0.5f) ? 0.f : 1.f;
        const float keep1 = (mv1 > 0.5f) ? 0.f : 1.f;
#pragma unroll
        for (int nfl = 0; nfl < 2; ++nfl) {
            const int b = nfl ? b1 : b0;
            const float keep = nfl ? keep1 : keep0;
            float hnv[4];
#pragma unroll
            for (int t = 0; t < 4; ++t) {
                const ushort_t* gp = (const ushort_t*)&gxv[t][nfl];
                const float gi = fmaf(acc[t][nfl][0], keep, bf2f(gp[0]) + bh[t][0]);
                const float gf = fmaf(acc[t][nfl][1], keep, bf2f(gp[1]) + bh[t][1]);
                const float gg = fmaf(acc[t][nfl][2], keep, bf2f(gp[2]) + bh[t][2]);
                const float go = fmaf(acc[t][nfl][3], keep, bf2f(gp[3]) + bh[t][3]);
                const float cn = sigmoid_fast(gf) * (creg[t][nfl] * keep)
                               + sigmoid_fast(gi) * tanh_fast(gg);
                const float hn = sigmoid_fast(go) * tanh_fast(cn);
                creg[t][nfl] = cn;
                hnv[t] = hn;
            }
            u32x2 hp2;
            hp2[0] = (uint_t)f2bf(hnv[0]) | ((uint_t)f2bf(hnv[1]) << 16);
            hp2[1] = (uint_t)f2bf(hnv[2]) | ((uint_t)f2bf(hnv[3]) << 16);
            ushort_t* dst = hid + (size_t)tl * BATCH * CELL_D
                          + (size_t)b * CELL_D + cell0;
            asm volatile("global_store_dwordx2 %0, %1, off sc0 sc1"
                         :: "v"(dst), "v"(hp2) : "memory");
            if (is_last && tl == Tc - 1) {
                float4 h4;
                h4.x = hnv[0]; h4.y = hnv[1]; h4.z = hnv[2]; h4.w = hnv[3];
                *(float4*)(hT_f32 + (size_t)b * CELL_D + cell0) = h4;
            }
        }

        if (tl == Tc - 1) break;   // last step: no flag/poll needed

        // ---- per-chain release: drain own stores, set flag, poll peers ----
        asm volatile("s_waitcnt vmcnt(0)" ::: "memory");
        const uint_t tgt = (uint_t)(tl + 1);
        if (lane == 0) {
            asm volatile("global_store_dword %0, %1, off sc0 sc1"
                         :: "v"(bar + w * 32 + blk), "v"(tgt) : "memory");
        }
        prefetch_step(tl + 1);     // gx/mask latency hides under the poll
        {
            const uint_t* fp = bar + w * 32 + (lane & 31);
            for (;;) {
                uint_t v;
                asm volatile("global_load_dword %0, %1, off sc0 sc1\n\t"
                             "s_waitcnt vmcnt(0)"
                             : "=v"(v) : "v"(fp) : "memory");
                if (__all((int)(v >= tgt))) break;
                __builtin_amdgcn_s_sleep(1);
            }
        }
        asm volatile("" ::: "memory");   // no load hoisting above the poll
    }

    // ---- write back c (float4, contiguous cells) ----
    {
        float4 o0, o1;
        o0.x = creg[0][0]; o0.y = creg[1][0]; o0.z = creg[2][0]; o0.w = creg[3][0];
        o1.x = creg[0][1]; o1.y = creg[1][1]; o1.z = creg[2][1]; o1.w = creg[3][1];
        *(float4*)(c_state + (size_t)b0 * CELL_D + cell0) = o0;
        *(float4*)(c_state + (size_t)b1 * CELL_D + cell0) = o1;
    }
}

// means = tanh(h @ W_mean^T + b_mean); log_std broadcast. h is bf16.
__global__ __launch_bounds__(256)
void mean_head(const ushort_t* __restrict__ hiddens, const float* __restrict__ W_mean,
               const float* __restrict__ b_mean, const float* __restrict__ log_std,
               float* __restrict__ means_out, float* __restrict__ logstd_out)
{
    __shared__ float Wm[8][516];
    const int tid = threadIdx.x;
#pragma unroll
    for (int i = 0; i < 16; ++i) {
        int idx = i * 256 + tid;
        Wm[idx >> 9][idx & 511] = W_mean[idx];
    }
    __syncthreads();
    const int r = tid >> 3, a = tid & 7;
    const size_t m = (size_t)blockIdx.x * 32 + r;
    const ushort_t* hp = hiddens + m * CELL_D;
    float acc = 0.f;
#pragma unroll 2
    for (int k8 = 0; k8 < 64; ++k8) {
        const uint4 v = *(const uint4*)(hp + k8 * 8);
        const ushort_t* pv = (const ushort_t*)&v;
        const float* wv = &Wm[a][k8 * 8];
#pragma unroll
        for (int e = 0; e < 8; ++e) acc = fmaf(bf2f(pv[e]), wv[e], acc);
    }
    means_out[m * ACT_D + a]  = tanhf(acc + b_mean[a]);
    logstd_out[m * ACT_D + a] = log_std[a];
}

extern "C" void kernel_launch(void* const* d_in, const int* in_sizes, int n_in,
                              void* d_out, int out_size, void* d_ws, size_t ws_size,
                              hipStream_t stream)
{
    const float* xs     = (const float*)d_in[0];
    const float* h0     = (const float*)d_in[1];
    const float* c0     = (const float*)d_in[2];
    const float* masks  = (const float*)d_in[3];
    const float* W_in   = (const float*)d_in[4];
    const float* b_in   = (const float*)d_in[5];
    const float* W_ih   = (const float*)d_in[6];
    const float* b_ih   = (const float*)d_in[7];
    const float* W_hh   = (const float*)d_in[8];
    const float* b_hh   = (const float*)d_in[9];
    const float* W_mean = (const float*)d_in[10];
    const float* b_mean = (const float*)d_in[11];
    const float* lstd   = (const float*)d_in[12];

    const int M = T_STEPS * BATCH;
    const size_t stateB = (size_t)BATCH * CELL_D * sizeof(float);   // 512 KiB

    const size_t szWhh  = (size_t)GATE_D * CELL_D * 2;   // 2 MiB
    const size_t szWih  = (size_t)GATE_D * HID_D * 2;    // 4 MiB
    const size_t szWin  = (size_t)HID_D * OBS_D * 2;     // 128 KiB
    const size_t szH0b  = (size_t)BATCH * CELL_D * 2;    // 256 KiB
    const size_t szBih  = (size_t)GATE_D * 4;            // 8 KiB
    const size_t szBar  = 1024;
    const size_t fixed  = szWhh + szWih + szWin + szH0b + szBih + szBar + stateB;

    const size_t per_tc = (size_t)BATCH * GATE_D * 2     // gx_p bf16: 1 MiB
                        + (size_t)BATCH * CELL_D * 2     // hid bf16
                        + (size_t)BATCH * HID_D * 2      // E bf16
                        + (size_t)BATCH * OBS_D * 2;     // xs_b
    int Tc = T_STEPS;
    while (Tc > 2 && fixed + per_tc * (size_t)Tc > ws_size) Tc >>= 1;

    char* p = (char*)d_ws;
    ushort_t* Whh_p = (ushort_t*)p;              p += szWhh;
    ushort_t* Wih_p = (ushort_t*)p;              p += szWih;
    ushort_t* Win_b = (ushort_t*)p;              p += szWin;
    ushort_t* h0b   = (ushort_t*)p;              p += szH0b;
    float*    bihp  = (float*)p;                 p += szBih;
    uint_t*   bar   = (uint_t*)p;                p += szBar;
    float*    c_state = (float*)p;               p += stateB;
    ushort_t* gx_p  = (ushort_t*)p;              p += (size_t)Tc * BATCH * GATE_D * 2;
    ushort_t* hid   = (ushort_t*)p;              p += (size_t)Tc * BATCH * CELL_D * 2;
    ushort_t* E     = (ushort_t*)p;              p += (size_t)Tc * BATCH * HID_D * 2;
    ushort_t* xs_b  = (ushort_t*)p;

    float* means_out  = (float*)d_out;
    float* logstd_out = means_out + (size_t)M * ACT_D;
    float* hT_out     = logstd_out + (size_t)M * ACT_D;
    float* cT_out     = hT_out + (size_t)BATCH * CELL_D;

    // ---- one-shot converts / permutes / state init ----
    permute_whh_rows<<<GATE_D, 256, 0, stream>>>(W_hh, Whh_p, CELL_D);
    permute_gate_rows<<<GATE_D, 256, 0, stream>>>(W_ih, Wih_p, HID_D);
    cvt_f32_bf16<<<(HID_D * OBS_D) / 2048, 256, 0, stream>>>(W_in, Win_b);
    cvt_f32_bf16<<<(BATCH * CELL_D) / 2048, 256, 0, stream>>>(h0, h0b);
    permute_bias<<<GATE_D / 256, 256, 0, stream>>>(b_ih, bihp);
    hipMemcpyAsync(c_state, c0, stateB, hipMemcpyDeviceToDevice, stream);

    const int chunks = T_STEPS / Tc;
    for (int ci = 0; ci < chunks; ++ci) {
        const int t0 = ci * Tc;
        const int Mc = Tc * BATCH;

        cvt_f32_bf16<<<(Mc * OBS_D) / 2048, 256, 0, stream>>>(
            xs + (size_t)t0 * BATCH * OBS_D, xs_b);

        gemm_mfma_nt<1><<<dim3(HID_D / 128, Mc / 128), 256, 0, stream>>>(
            xs_b, Win_b, b_in, E, HID_D, OBS_D);

        gemm_mfma_nt<2><<<dim3(GATE_D / 128, Mc / 128), 256, 0, stream>>>(
            E, Wih_p, bihp, gx_p, GATE_D, HID_D);

        hipMemsetAsync(bar, 0, 1024, stream);
        const ushort_t* h_init = (ci == 0) ? h0b
                               : hid + (size_t)(Tc - 1) * BATCH * CELL_D;
        lstm_scan<<<SCAN_BLOCKS, 512, 0, stream>>>(
            gx_p, Whh_p, b_hh, masks + (size_t)t0 * BATCH, h_init,
            c_state, hid, hT_out, Tc, (ci == chunks - 1) ? 1 : 0, bar);

        mean_head<<<Mc / 32, 256, 0, stream>>>(
            hid, W_mean, b_mean, lstd,
            means_out + (size_t)t0 * BATCH * ACT_D,
            logstd_out + (size_t)t0 * BATCH * ACT_D);
    }

    hipMemcpyAsync(cT_out, c_state, stateB, hipMemcpyDeviceToDevice, stream);
}

// Round 11
// 5927.168 us; speedup vs baseline: 1.2480x; 1.2480x over previous
//
#include <hip/hip_runtime.h>
#include <cstdint>
#include <cstddef>

typedef unsigned short ushort_t;
typedef unsigned int uint_t;
typedef __attribute__((ext_vector_type(8))) __bf16 bf16x8;
typedef __attribute__((ext_vector_type(4))) float f32x4;
typedef __attribute__((ext_vector_type(2))) unsigned int u32x2;

static constexpr int T_STEPS = 512;
static constexpr int BATCH   = 256;
static constexpr int OBS_D   = 64;
static constexpr int ACT_D   = 8;
static constexpr int HID_D   = 1024;
static constexpr int CELL_D  = 512;
static constexpr int GATE_D  = 4 * CELL_D;   // 2048
static constexpr int SCAN_BLOCKS = 32;       // each owns 64 P-cols = 16 cells

__device__ __forceinline__ float bf2f(ushort_t s) {
    uint_t u = ((uint_t)s) << 16;
    float f;
    __builtin_memcpy(&f, &u, 4);
    return f;
}
__device__ __forceinline__ ushort_t f2bf(float x) {
    uint_t u;
    __builtin_memcpy(&u, &x, 4);
    u += 0x7fffu + ((u >> 16) & 1u);   // RNE
    return (ushort_t)(u >> 16);
}

// ---- fast transcendentals (v_exp_f32 / v_rcp_f32; exact at saturation) ----
__device__ __forceinline__ float sigmoid_fast(float x) {
    return __builtin_amdgcn_rcpf(1.f + __expf(-x));
}
__device__ __forceinline__ float tanh_fast(float x) {
    const float e = __expf(-2.f * fabsf(x));          // in [0,1]
    const float r = (1.f - e) * __builtin_amdgcn_rcpf(1.f + e);
    return copysignf(r, x);
}

// ---- f32 -> bf16 bulk convert (8/thread; n multiple of 2048) ----
__global__ __launch_bounds__(256)
void cvt_f32_bf16(const float* __restrict__ in, ushort_t* __restrict__ out)
{
    const size_t i = ((size_t)blockIdx.x * 256 + threadIdx.x) * 8;
    const float4 v0 = *(const float4*)(in + i);
    const float4 v1 = *(const float4*)(in + i + 4);
    uint4 p;
    p.x = (uint_t)f2bf(v0.x) | ((uint_t)f2bf(v0.y) << 16);
    p.y = (uint_t)f2bf(v0.z) | ((uint_t)f2bf(v0.w) << 16);
    p.z = (uint_t)f2bf(v1.x) | ((uint_t)f2bf(v1.y) << 16);
    p.w = (uint_t)f2bf(v1.z) | ((uint_t)f2bf(v1.w) << 16);
    *(uint4*)(out + i) = p;
}

// Gate-major [4*C][K] f32 -> cell-major permuted bf16: Wp[P=c*4+g][k]
// (used for W_ih -> gx_p layout: gates of cell c at gx[c*4+g])
__global__ __launch_bounds__(256)
void permute_gate_rows(const float* __restrict__ W, ushort_t* __restrict__ Wp, int K)
{
    const int P = blockIdx.x;               // 0..2047
    const int c = P >> 2, g = P & 3;
    const float* src = W + (size_t)(g * CELL_D + c) * K;
    ushort_t* dst = Wp + (size_t)P * K;
    for (int k = threadIdx.x; k < K; k += 256) dst[k] = f2bf(src[k]);
}

// W_hh permute for the scan's lane->cell mapping:
// global row blk*64 + t*16 + q*4 + r  <-  W_hh[gate r][cell blk*16 + q*4 + t]
// so lane (q,s) tile t reg r = gate r of cell blk*16+q*4+t (4 CONTIGUOUS cells/lane).
__global__ __launch_bounds__(256)
void permute_whh_rows(const float* __restrict__ W, ushort_t* __restrict__ Wp, int K)
{
    const int P = blockIdx.x;               // 0..2047
    const int blk = P >> 6, rl = P & 63;
    const int t = rl >> 4, qq = (rl >> 2) & 3, r = rl & 3;
    const float* src = W + (size_t)(r * CELL_D + blk * 16 + qq * 4 + t) * K;
    ushort_t* dst = Wp + (size_t)P * K;
    for (int k = threadIdx.x; k < K; k += 256) dst[k] = f2bf(src[k]);
}

__global__ __launch_bounds__(256)
void permute_bias(const float* __restrict__ b, float* __restrict__ bp)
{
    const int P = blockIdx.x * 256 + threadIdx.x;   // grid 8
    bp[P] = b[(P & 3) * CELL_D + (P >> 2)];
}

// ---- MFMA bf16 GEMM: C[m][n] = sum_k A[m][k]*B[n][k] + bias[n] ----
// 128x128 tile, BK=32, 4 waves, 4x4 16x16x32 frags/wave.
// OUT_MODE: 0 = f32, 1 = bf16+ReLU, 2 = bf16 linear
template<int OUT_MODE>
__global__ __launch_bounds__(256)
void gemm_mfma_nt(const ushort_t* __restrict__ A, const ushort_t* __restrict__ B,
                  const float* __restrict__ bias, void* __restrict__ out_,
                  int N, int K)
{
    __shared__ __align__(16) ushort_t As[128 * 32];
    __shared__ __align__(16) ushort_t Bs[128 * 32];
    const int tid  = threadIdx.x;
    const int lane = tid & 63;
    const int wid  = tid >> 6;
    const int wr   = (wid >> 1) * 64;
    const int wc   = (wid & 1) * 64;
    const int m0 = blockIdx.y * 128;
    const int n0 = blockIdx.x * 128;

    const int srow = tid >> 2;
    const int sv   = tid & 3;
    const int fr   = lane & 15;
    const int fo   = lane >> 4;

    f32x4 acc[4][4];
#pragma unroll
    for (int i = 0; i < 4; ++i)
#pragma unroll
        for (int j = 0; j < 4; ++j) acc[i][j] = (f32x4){0.f, 0.f, 0.f, 0.f};

    const ushort_t* Apt = A + (size_t)(m0 + srow) * K + sv * 8;
    const ushort_t* Bpt = B + (size_t)(n0 + srow) * K + sv * 8;
    uint4* As4 = (uint4*)As;
    uint4* Bs4 = (uint4*)Bs;
    const bf16x8* Af = (const bf16x8*)As;
    const bf16x8* Bf = (const bf16x8*)Bs;

    for (int k0 = 0; k0 < K; k0 += 32) {
        const uint4 a0 = *(const uint4*)(Apt + k0);
        const uint4 a1 = *(const uint4*)(Apt + (size_t)64 * K + k0);
        const uint4 b0 = *(const uint4*)(Bpt + k0);
        const uint4 b1 = *(const uint4*)(Bpt + (size_t)64 * K + k0);
        __syncthreads();
        As4[srow * 4 + sv]        = a0;
        As4[(64 + srow) * 4 + sv] = a1;
        Bs4[srow * 4 + sv]        = b0;
        Bs4[(64 + srow) * 4 + sv] = b1;
        __syncthreads();

        bf16x8 av[4], bv[4];
#pragma unroll
        for (int m = 0; m < 4; ++m) av[m] = Af[(wr + m * 16 + fr) * 4 + fo];
#pragma unroll
        for (int n = 0; n < 4; ++n) bv[n] = Bf[(wc + n * 16 + fr) * 4 + fo];
#pragma unroll
        for (int m = 0; m < 4; ++m)
#pragma unroll
            for (int n = 0; n < 4; ++n)
                acc[m][n] = __builtin_amdgcn_mfma_f32_16x16x32_bf16(
                    av[m], bv[n], acc[m][n], 0, 0, 0);
    }

#pragma unroll
    for (int n = 0; n < 4; ++n) {
        const int col = n0 + wc + n * 16 + fr;
        const float bvv = bias[col];
#pragma unroll
        for (int m = 0; m < 4; ++m) {
            const int row0 = m0 + wr + m * 16 + fo * 4;
#pragma unroll
            for (int r = 0; r < 4; ++r) {
                const float v = acc[m][n][r] + bvv;
                if constexpr (OUT_MODE == 1)
                    ((ushort_t*)out_)[(size_t)(row0 + r) * N + col] = f2bf(fmaxf(v, 0.f));
                else if constexpr (OUT_MODE == 2)
                    ((ushort_t*)out_)[(size_t)(row0 + r) * N + col] = f2bf(v);
                else
                    ((float*)out_)[(size_t)(row0 + r) * N + col] = v;
            }
        }
    }
}

// ---- h-read pipeline helpers (quarter = 4 K-steps, 8x16B loads) ----
__device__ __forceinline__ void loadq(uint4 (&d0)[4], uint4 (&d1)[4],
                                      const ushort_t* hr0, const ushort_t* hr1,
                                      int base)
{
#pragma unroll
    for (int j = 0; j < 4; ++j) {
        d0[j] = *(const uint4*)(hr0 + (base + j) * 32);
        d1[j] = *(const uint4*)(hr1 + (base + j) * 32);
    }
}

__device__ __forceinline__ void compq(const uint4 (&d0)[4], const uint4 (&d1)[4],
                                      const char* wsrow, int q16, int xmask,
                                      int base, f32x4 (&acc)[4][2])
{
#pragma unroll
    for (int j = 0; j < 4; ++j) {
        bf16x8 hv0, hv1;
        __builtin_memcpy(&hv0, &d0[j], 16);
        __builtin_memcpy(&hv1, &d1[j], 16);
        const int koff = ((base + j) * 64 + q16) ^ xmask;
#pragma unroll
        for (int Pt = 0; Pt < 4; ++Pt) {
            const bf16x8 av = *(const bf16x8*)(wsrow + Pt * 16 * 1024 + koff);
            acc[Pt][0] = __builtin_amdgcn_mfma_f32_16x16x32_bf16(av, hv0, acc[Pt][0], 0, 0, 0);
            acc[Pt][1] = __builtin_amdgcn_mfma_f32_16x16x32_bf16(av, hv1, acc[Pt][1], 0, 0, 0);
        }
    }
}

// ---- persistent LSTM scan, 32 blocks x 512 threads, PER-WAVE CHAINS ----
// Round-9 compute core (wreg revert: r10 showed compiler moves the W array
// to AGPR/scratch, regressing 19%) + PIPELINED RENDEZVOUS:
//  - quarter k of the K-loop (ks 4k..4k+3 = h cells 128k..128k+127) needs h
//    only from producer blocks 8k..8k+7 -> wait per 8-flag GROUP, not all 32.
//    waitg(g) uses one cached 32-lane ballot: in steady state a single
//    flag-load round satisfies all four groups (no extra LLC traffic); when
//    peers lag, quarters 1-3's waits hide under earlier loads+MFMAs.
//  - the end-of-step poll is GONE (its work is next step's waitg(0)), so the
//    gx prefetch no longer sits in the poll's vmcnt(0) shadow: it now issues
//    after waitg(0) and its latency hides under ~4us of h-load+MFMA.
__global__ __launch_bounds__(512)
void lstm_scan(const ushort_t* __restrict__ gx_p,   // [Tc*256][2048] bf16 (P-cols)
               const ushort_t* __restrict__ Whh_p,  // [2048][512] bf16 (scan permute)
               const float* __restrict__ b_hh,      // [2048] f32 gate-major
               const float* __restrict__ masks_c,   // [Tc*256]
               const ushort_t* h_init,              // [256][512] bf16
               float* __restrict__ c_state,         // [256][512] f32 in/out
               ushort_t* hid,                       // [Tc][256][512] bf16 out
               float* __restrict__ hT_f32,
               int Tc, int is_last,
               uint_t* __restrict__ bar)            // flags[8][32], 128B/chain
{
    __shared__ __align__(16) ushort_t Ws[64 * 512];   // 64 KiB, XOR-swizzled

    const int tid  = threadIdx.x;
    const int lane = tid & 63;
    const int w    = tid >> 6;      // wave/chain 0..7 -> batch rows [w*32,+32)
    const int q    = lane >> 4;     // 0..3
    const int s    = lane & 15;
    const int blk  = blockIdx.x;
    const int xmask = (s & 7) << 4; // LDS XOR swizzle for A-frag reads
    const int q16  = q * 16;
    const int cell0 = blk * 16 + q * 4;   // lane's 4 contiguous cells

    // ---- W slice -> LDS (swizzled); row stride 1024 B ----
    for (int idx = tid; idx < 64 * 64; idx += 512) {
        const int row = idx >> 6;          // P-local 0..63
        const int c16 = idx & 63;          // 16B chunk
        const uint4 v = *(const uint4*)(Whh_p + (size_t)(blk * 64 + row) * CELL_D + c16 * 8);
        *(uint4*)((char*)Ws + row * 1024 + ((c16 * 16) ^ ((row & 7) << 4))) = v;
    }

    const int b0 = w * 32 + s;        // nfl=0 batch row
    const int b1 = b0 + 16;           // nfl=1

    // ---- per-lane state (float4: cells contiguous) ----
    float creg[4][2];
    {
        const float4 c40 = *(const float4*)(c_state + (size_t)b0 * CELL_D + cell0);
        const float4 c41 = *(const float4*)(c_state + (size_t)b1 * CELL_D + cell0);
        creg[0][0] = c40.x; creg[1][0] = c40.y; creg[2][0] = c40.z; creg[3][0] = c40.w;
        creg[0][1] = c41.x; creg[1][1] = c41.y; creg[2][1] = c41.z; creg[3][1] = c41.w;
    }
    float bh[4][4];
#pragma unroll
    for (int r = 0; r < 4; ++r) {
        const float4 b4 = *(const float4*)(b_hh + r * CELL_D + cell0);
        bh[0][r] = b4.x; bh[1][r] = b4.y; bh[2][r] = b4.z; bh[3][r] = b4.w;
    }

    // ---- per-chain gx/mask prefetch state ----
    float mv0, mv1;
    uint2 gxv[4][2];
    auto prefetch_step = [&](int TL) {
        const ushort_t* g0 = gx_p + ((size_t)TL * BATCH + b0) * GATE_D + blk * 64 + q * 16;
        const ushort_t* g1 = g0 + (size_t)16 * GATE_D;
#pragma unroll
        for (int t = 0; t < 4; ++t) {
            gxv[t][0] = *(const uint2*)(g0 + t * 4);
            gxv[t][1] = *(const uint2*)(g1 + t * 4);
        }
        mv0 = masks_c[(size_t)TL * BATCH + b0];
        mv1 = masks_c[(size_t)TL * BATCH + b1];
    };

    const char* wsrow = (const char*)Ws + s * 1024;
    __syncthreads();                  // Ws staging complete (only sync)

    // ---- phase stagger: chain w delays ~w*0.8us once (kept from round 9) ----
    for (int i = 0; i < w * 4; ++i) __builtin_amdgcn_s_sleep(8);

    for (int tl = 0; tl < Tc; ++tl) {
        const ushort_t* hp = (tl == 0) ? h_init
                                       : hid + (size_t)(tl - 1) * BATCH * CELL_D;
        const ushort_t* hr0 = hp + (size_t)b0 * CELL_D + q * 8;
        const ushort_t* hr1 = hp + (size_t)b1 * CELL_D + q * 8;

        // ---- per-quarter flag-group wait (flag >= tl means step tl-1 done) ----
        uint64_t ready = 0;
        const uint_t tgt_in = (uint_t)tl;
        auto waitg = [&](int g) {
            const uint64_t need = 0xFFull << (g * 8);
            if ((ready & need) != need) {
                const uint_t* fp = bar + w * 32 + (lane & 31);
                for (;;) {
                    uint_t v;
                    asm volatile("global_load_dword %0, %1, off sc0 sc1\n\t"
                                 "s_waitcnt vmcnt(0)"
                                 : "=v"(v) : "v"(fp) : "memory");
                    ready = __ballot((int)(v >= tgt_in)) & 0xFFFFFFFFull;
                    if ((ready & need) == need) break;
                    __builtin_amdgcn_s_sleep(1);
                }
            }
            asm volatile("" ::: "memory");   // no load hoisting above the check
        };

        f32x4 acc[4][2];
#pragma unroll
        for (int t = 0; t < 4; ++t) {
            acc[t][0] = (f32x4){0.f, 0.f, 0.f, 0.f};
            acc[t][1] = (f32x4){0.f, 0.f, 0.f, 0.f};
        }

        // ---- pipelined: waitg(g) -> loadq(g) -> compq(g-1), gx under MFMAs ----
        uint4 A0[4], A1[4], B0[4], B1[4];
        if (tl) waitg(0);
        loadq(A0, A1, hr0, hr1, 0);
        prefetch_step(tl);             // consumed at cell update (~4us later)
        if (tl) waitg(1);
        loadq(B0, B1, hr0, hr1, 4);
        compq(A0, A1, wsrow, q16, xmask, 0, acc);
        if (tl) waitg(2);
        loadq(A0, A1, hr0, hr1, 8);
        compq(B0, B1, wsrow, q16, xmask, 4, acc);
        if (tl) waitg(3);
        loadq(B0, B1, hr0, hr1, 12);
        compq(A0, A1, wsrow, q16, xmask, 8, acc);
        compq(B0, B1, wsrow, q16, xmask, 12, acc);

        // ---- cell update (mask post-MFMA; exact for keep in {0,1}) ----
        const float keep0 = (mv0 > 0.5f) ? 0.f : 1.f;
        const float keep1 = (mv1 > 0.5f) ? 0.f : 1.f;
#pragma unroll
        for (int nfl = 0; nfl < 2; ++nfl) {
            const int b = nfl ? b1 : b0;
            const float keep = nfl ? keep1 : keep0;
            float hnv[4];
#pragma unroll
            for (int t = 0; t < 4; ++t) {
                const ushort_t* gp = (const ushort_t*)&gxv[t][nfl];
                const float gi = fmaf(acc[t][nfl][0], keep, bf2f(gp[0]) + bh[t][0]);
                const float gf = fmaf(acc[t][nfl][1], keep, bf2f(gp[1]) + bh[t][1]);
                const float gg = fmaf(acc[t][nfl][2], keep, bf2f(gp[2]) + bh[t][2]);
                const float go = fmaf(acc[t][nfl][3], keep, bf2f(gp[3]) + bh[t][3]);
                const float cn = sigmoid_fast(gf) * (creg[t][nfl] * keep)
                               + sigmoid_fast(gi) * tanh_fast(gg);
                const float hn = sigmoid_fast(go) * tanh_fast(cn);
                creg[t][nfl] = cn;
                hnv[t] = hn;
            }
            u32x2 hp2;
            hp2[0] = (uint_t)f2bf(hnv[0]) | ((uint_t)f2bf(hnv[1]) << 16);
            hp2[1] = (uint_t)f2bf(hnv[2]) | ((uint_t)f2bf(hnv[3]) << 16);
            ushort_t* dst = hid + (size_t)tl * BATCH * CELL_D
                          + (size_t)b * CELL_D + cell0;
            asm volatile("global_store_dwordx2 %0, %1, off sc0 sc1"
                         :: "v"(dst), "v"(hp2) : "memory");
            if (is_last && tl == Tc - 1) {
                float4 h4;
                h4.x = hnv[0]; h4.y = hnv[1]; h4.z = hnv[2]; h4.w = hnv[3];
                *(float4*)(hT_f32 + (size_t)b * CELL_D + cell0) = h4;
            }
        }

        if (tl == Tc - 1) break;   // last step: no release needed

        // ---- release: drain own h-stores, then set flag = tl+1 ----
        asm volatile("s_waitcnt vmcnt(0)" ::: "memory");
        {
            const uint_t tgt = (uint_t)(tl + 1);
            if (lane == 0) {
                asm volatile("global_store_dword %0, %1, off sc0 sc1"
                             :: "v"(bar + w * 32 + blk), "v"(tgt) : "memory");
            }
        }
    }

    // ---- write back c (float4, contiguous cells) ----
    {
        float4 o0, o1;
        o0.x = creg[0][0]; o0.y = creg[1][0]; o0.z = creg[2][0]; o0.w = creg[3][0];
        o1.x = creg[0][1]; o1.y = creg[1][1]; o1.z = creg[2][1]; o1.w = creg[3][1];
        *(float4*)(c_state + (size_t)b0 * CELL_D + cell0) = o0;
        *(float4*)(c_state + (size_t)b1 * CELL_D + cell0) = o1;
    }
}

// means = tanh(h @ W_mean^T + b_mean); log_std broadcast. h is bf16.
__global__ __launch_bounds__(256)
void mean_head(const ushort_t* __restrict__ hiddens, const float* __restrict__ W_mean,
               const float* __restrict__ b_mean, const float* __restrict__ log_std,
               float* __restrict__ means_out, float* __restrict__ logstd_out)
{
    __shared__ float Wm[8][516];
    const int tid = threadIdx.x;
#pragma unroll
    for (int i = 0; i < 16; ++i) {
        int idx = i * 256 + tid;
        Wm[idx >> 9][idx & 511] = W_mean[idx];
    }
    __syncthreads();
    const int r = tid >> 3, a = tid & 7;
    const size_t m = (size_t)blockIdx.x * 32 + r;
    const ushort_t* hp = hiddens + m * CELL_D;
    float acc = 0.f;
#pragma unroll 2
    for (int k8 = 0; k8 < 64; ++k8) {
        const uint4 v = *(const uint4*)(hp + k8 * 8);
        const ushort_t* pv = (const ushort_t*)&v;
        const float* wv = &Wm[a][k8 * 8];
#pragma unroll
        for (int e = 0; e < 8; ++e) acc = fmaf(bf2f(pv[e]), wv[e], acc);
    }
    means_out[m * ACT_D + a]  = tanhf(acc + b_mean[a]);
    logstd_out[m * ACT_D + a] = log_std[a];
}

extern "C" void kernel_launch(void* const* d_in, const int* in_sizes, int n_in,
                              void* d_out, int out_size, void* d_ws, size_t ws_size,
                              hipStream_t stream)
{
    const float* xs     = (const float*)d_in[0];
    const float* h0     = (const float*)d_in[1];
    const float* c0     = (const float*)d_in[2];
    const float* masks  = (const float*)d_in[3];
    const float* W_in   = (const float*)d_in[4];
    const float* b_in   = (const float*)d_in[5];
    const float* W_ih   = (const float*)d_in[6];
    const float* b_ih   = (const float*)d_in[7];
    const float* W_hh   = (const float*)d_in[8];
    const float* b_hh   = (const float*)d_in[9];
    const float* W_mean = (const float*)d_in[10];
    const float* b_mean = (const float*)d_in[11];
    const float* lstd   = (const float*)d_in[12];

    const int M = T_STEPS * BATCH;
    const size_t stateB = (size_t)BATCH * CELL_D * sizeof(float);   // 512 KiB

    const size_t szWhh  = (size_t)GATE_D * CELL_D * 2;   // 2 MiB
    const size_t szWih  = (size_t)GATE_D * HID_D * 2;    // 4 MiB
    const size_t szWin  = (size_t)HID_D * OBS_D * 2;     // 128 KiB
    const size_t szH0b  = (size_t)BATCH * CELL_D * 2;    // 256 KiB
    const size_t szBih  = (size_t)GATE_D * 4;            // 8 KiB
    const size_t szBar  = 1024;
    const size_t fixed  = szWhh + szWih + szWin + szH0b + szBih + szBar + stateB;

    const size_t per_tc = (size_t)BATCH * GATE_D * 2     // gx_p bf16: 1 MiB
                        + (size_t)BATCH * CELL_D * 2     // hid bf16
                        + (size_t)BATCH * HID_D * 2      // E bf16
                        + (size_t)BATCH * OBS_D * 2;     // xs_b
    int Tc = T_STEPS;
    while (Tc > 2 && fixed + per_tc * (size_t)Tc > ws_size) Tc >>= 1;

    char* p = (char*)d_ws;
    ushort_t* Whh_p = (ushort_t*)p;              p += szWhh;
    ushort_t* Wih_p = (ushort_t*)p;              p += szWih;
    ushort_t* Win_b = (ushort_t*)p;              p += szWin;
    ushort_t* h0b   = (ushort_t*)p;              p += szH0b;
    float*    bihp  = (float*)p;                 p += szBih;
    uint_t*   bar   = (uint_t*)p;                p += szBar;
    float*    c_state = (float*)p;               p += stateB;
    ushort_t* gx_p  = (ushort_t*)p;              p += (size_t)Tc * BATCH * GATE_D * 2;
    ushort_t* hid   = (ushort_t*)p;              p += (size_t)Tc * BATCH * CELL_D * 2;
    ushort_t* E     = (ushort_t*)p;              p += (size_t)Tc * BATCH * HID_D * 2;
    ushort_t* xs_b  = (ushort_t*)p;

    float* means_out  = (float*)d_out;
    float* logstd_out = means_out + (size_t)M * ACT_D;
    float* hT_out     = logstd_out + (size_t)M * ACT_D;
    float* cT_out     = hT_out + (size_t)BATCH * CELL_D;

    // ---- one-shot converts / permutes / state init ----
    permute_whh_rows<<<GATE_D, 256, 0, stream>>>(W_hh, Whh_p, CELL_D);
    permute_gate_rows<<<GATE_D, 256, 0, stream>>>(W_ih, Wih_p, HID_D);
    cvt_f32_bf16<<<(HID_D * OBS_D) / 2048, 256, 0, stream>>>(W_in, Win_b);
    cvt_f32_bf16<<<(BATCH * CELL_D) / 2048, 256, 0, stream>>>(h0, h0b);
    permute_bias<<<GATE_D / 256, 256, 0, stream>>>(b_ih, bihp);
    hipMemcpyAsync(c_state, c0, stateB, hipMemcpyDeviceToDevice, stream);

    const int chunks = T_STEPS / Tc;
    for (int ci = 0; ci < chunks; ++ci) {
        const int t0 = ci * Tc;
        const int Mc = Tc * BATCH;

        cvt_f32_bf16<<<(Mc * OBS_D) / 2048, 256, 0, stream>>>(
            xs + (size_t)t0 * BATCH * OBS_D, xs_b);

        gemm_mfma_nt<1><<<dim3(HID_D / 128, Mc / 128), 256, 0, stream>>>(
            xs_b, Win_b, b_in, E, HID_D, OBS_D);

        gemm_mfma_nt<2><<<dim3(GATE_D / 128, Mc / 128), 256, 0, stream>>>(
            E, Wih_p, bihp, gx_p, GATE_D, HID_D);

        hipMemsetAsync(bar, 0, 1024, stream);
        const ushort_t* h_init = (ci == 0) ? h0b
                               : hid + (size_t)(Tc - 1) * BATCH * CELL_D;
        lstm_scan<<<SCAN_BLOCKS, 512, 0, stream>>>(
            gx_p, Whh_p, b_hh, masks + (size_t)t0 * BATCH, h_init,
            c_state, hid, hT_out, Tc, (ci == chunks - 1) ? 1 : 0, bar);

        mean_head<<<Mc / 32, 256, 0, stream>>>(
            hid, W_mean, b_mean, lstd,
            means_out + (size_t)t0 * BATCH * ACT_D,
            logstd_out + (size_t)t0 * BATCH * ACT_D);
    }

    hipMemcpyAsync(cT_out, c_state, stateB, hipMemcpyDeviceToDevice, stream);
}

// Round 12
// 3713.898 us; speedup vs baseline: 1.9917x; 1.5959x over previous
//
#include <hip/hip_runtime.h>
#include <cstdint>
#include <cstddef>

typedef unsigned short ushort_t;
typedef unsigned int uint_t;
typedef __attribute__((ext_vector_type(8))) __bf16 bf16x8;
typedef __attribute__((ext_vector_type(4))) float f32x4;
typedef __attribute__((ext_vector_type(2))) unsigned int u32x2;

static constexpr int T_STEPS = 512;
static constexpr int BATCH   = 256;
static constexpr int OBS_D   = 64;
static constexpr int ACT_D   = 8;
static constexpr int HID_D   = 1024;
static constexpr int CELL_D  = 512;
static constexpr int GATE_D  = 4 * CELL_D;   // 2048
static constexpr int SCAN_BLOCKS = 256;      // 8 batch-groups x 32 cell-slices

__device__ __forceinline__ float bf2f(ushort_t s) {
    uint_t u = ((uint_t)s) << 16;
    float f;
    __builtin_memcpy(&f, &u, 4);
    return f;
}
__device__ __forceinline__ ushort_t f2bf(float x) {
    uint_t u;
    __builtin_memcpy(&u, &x, 4);
    u += 0x7fffu + ((u >> 16) & 1u);   // RNE
    return (ushort_t)(u >> 16);
}

// ---- fast transcendentals (v_exp_f32 / v_rcp_f32; exact at saturation) ----
__device__ __forceinline__ float sigmoid_fast(float x) {
    return __builtin_amdgcn_rcpf(1.f + __expf(-x));
}
__device__ __forceinline__ float tanh_fast(float x) {
    const float e = __expf(-2.f * fabsf(x));          // in [0,1]
    const float r = (1.f - e) * __builtin_amdgcn_rcpf(1.f + e);
    return copysignf(r, x);
}

// ---- f32 -> bf16 bulk convert (8/thread; n multiple of 2048) ----
__global__ __launch_bounds__(256)
void cvt_f32_bf16(const float* __restrict__ in, ushort_t* __restrict__ out)
{
    const size_t i = ((size_t)blockIdx.x * 256 + threadIdx.x) * 8;
    const float4 v0 = *(const float4*)(in + i);
    const float4 v1 = *(const float4*)(in + i + 4);
    uint4 p;
    p.x = (uint_t)f2bf(v0.x) | ((uint_t)f2bf(v0.y) << 16);
    p.y = (uint_t)f2bf(v0.z) | ((uint_t)f2bf(v0.w) << 16);
    p.z = (uint_t)f2bf(v1.x) | ((uint_t)f2bf(v1.y) << 16);
    p.w = (uint_t)f2bf(v1.z) | ((uint_t)f2bf(v1.w) << 16);
    *(uint4*)(out + i) = p;
}

// Gate-major [4*C][K] f32 -> cell-major permuted bf16: Wp[P=c*4+g][k]
// (used for W_ih -> gx_p layout: gates of cell c at gx[c*4+g])
__global__ __launch_bounds__(256)
void permute_gate_rows(const float* __restrict__ W, ushort_t* __restrict__ Wp, int K)
{
    const int P = blockIdx.x;               // 0..2047
    const int c = P >> 2, g = P & 3;
    const float* src = W + (size_t)(g * CELL_D + c) * K;
    ushort_t* dst = Wp + (size_t)P * K;
    for (int k = threadIdx.x; k < K; k += 256) dst[k] = f2bf(src[k]);
}

// W_hh permute for the 256-block scan's lane->cell mapping:
// global row j*64 + t*16 + q*4 + r  <-  W_hh[gate r][cell j*16 + t*4 + q]
// Wave w(=t) lane (q,s): acc reg r = gate r of cell j*16 + w*4 + q, so the
// four q-lanes of a wave hold 4 CONTIGUOUS cells (shfl-packed for 8B stores).
__global__ __launch_bounds__(256)
void permute_whh_rows(const float* __restrict__ W, ushort_t* __restrict__ Wp, int K)
{
    const int P = blockIdx.x;               // 0..2047
    const int blk = P >> 6, rl = P & 63;
    const int t = rl >> 4, qq = (rl >> 2) & 3, r = rl & 3;
    const float* src = W + (size_t)(r * CELL_D + blk * 16 + t * 4 + qq) * K;
    ushort_t* dst = Wp + (size_t)P * K;
    for (int k = threadIdx.x; k < K; k += 256) dst[k] = f2bf(src[k]);
}

__global__ __launch_bounds__(256)
void permute_bias(const float* __restrict__ b, float* __restrict__ bp)
{
    const int P = blockIdx.x * 256 + threadIdx.x;   // grid 8
    bp[P] = b[(P & 3) * CELL_D + (P >> 2)];
}

// ---- MFMA bf16 GEMM: C[m][n] = sum_k A[m][k]*B[n][k] + bias[n] ----
// 128x128 tile, BK=32, 4 waves, 4x4 16x16x32 frags/wave.
// OUT_MODE: 0 = f32, 1 = bf16+ReLU, 2 = bf16 linear
template<int OUT_MODE>
__global__ __launch_bounds__(256)
void gemm_mfma_nt(const ushort_t* __restrict__ A, const ushort_t* __restrict__ B,
                  const float* __restrict__ bias, void* __restrict__ out_,
                  int N, int K)
{
    __shared__ __align__(16) ushort_t As[128 * 32];
    __shared__ __align__(16) ushort_t Bs[128 * 32];
    const int tid  = threadIdx.x;
    const int lane = tid & 63;
    const int wid  = tid >> 6;
    const int wr   = (wid >> 1) * 64;
    const int wc   = (wid & 1) * 64;
    const int m0 = blockIdx.y * 128;
    const int n0 = blockIdx.x * 128;

    const int srow = tid >> 2;
    const int sv   = tid & 3;
    const int fr   = lane & 15;
    const int fo   = lane >> 4;

    f32x4 acc[4][4];
#pragma unroll
    for (int i = 0; i < 4; ++i)
#pragma unroll
        for (int j = 0; j < 4; ++j) acc[i][j] = (f32x4){0.f, 0.f, 0.f, 0.f};

    const ushort_t* Apt = A + (size_t)(m0 + srow) * K + sv * 8;
    const ushort_t* Bpt = B + (size_t)(n0 + srow) * K + sv * 8;
    uint4* As4 = (uint4*)As;
    uint4* Bs4 = (uint4*)Bs;
    const bf16x8* Af = (const bf16x8*)As;
    const bf16x8* Bf = (const bf16x8*)Bs;

    for (int k0 = 0; k0 < K; k0 += 32) {
        const uint4 a0 = *(const uint4*)(Apt + k0);
        const uint4 a1 = *(const uint4*)(Apt + (size_t)64 * K + k0);
        const uint4 b0 = *(const uint4*)(Bpt + k0);
        const uint4 b1 = *(const uint4*)(Bpt + (size_t)64 * K + k0);
        __syncthreads();
        As4[srow * 4 + sv]        = a0;
        As4[(64 + srow) * 4 + sv] = a1;
        Bs4[srow * 4 + sv]        = b0;
        Bs4[(64 + srow) * 4 + sv] = b1;
        __syncthreads();

        bf16x8 av[4], bv[4];
#pragma unroll
        for (int m = 0; m < 4; ++m) av[m] = Af[(wr + m * 16 + fr) * 4 + fo];
#pragma unroll
        for (int n = 0; n < 4; ++n) bv[n] = Bf[(wc + n * 16 + fr) * 4 + fo];
#pragma unroll
        for (int m = 0; m < 4; ++m)
#pragma unroll
            for (int n = 0; n < 4; ++n)
                acc[m][n] = __builtin_amdgcn_mfma_f32_16x16x32_bf16(
                    av[m], bv[n], acc[m][n], 0, 0, 0);
    }

#pragma unroll
    for (int n = 0; n < 4; ++n) {
        const int col = n0 + wc + n * 16 + fr;
        const float bvv = bias[col];
#pragma unroll
        for (int m = 0; m < 4; ++m) {
            const int row0 = m0 + wr + m * 16 + fo * 4;
#pragma unroll
            for (int r = 0; r < 4; ++r) {
                const float v = acc[m][n][r] + bvv;
                if constexpr (OUT_MODE == 1)
                    ((ushort_t*)out_)[(size_t)(row0 + r) * N + col] = f2bf(fmaxf(v, 0.f));
                else if constexpr (OUT_MODE == 2)
                    ((ushort_t*)out_)[(size_t)(row0 + r) * N + col] = f2bf(v);
                else
                    ((float*)out_)[(size_t)(row0 + r) * N + col] = v;
            }
        }
    }
}

// ---- h-read pipeline helpers (quarter = 4 K-steps, 8x16B loads) ----
__device__ __forceinline__ void loadq(uint4 (&d0)[4], uint4 (&d1)[4],
                                      const ushort_t* hr0, const ushort_t* hr1,
                                      int base)
{
#pragma unroll
    for (int j = 0; j < 4; ++j) {
        d0[j] = *(const uint4*)(hr0 + (base + j) * 32);
        d1[j] = *(const uint4*)(hr1 + (base + j) * 32);
    }
}

// single 16-row tile (wave's own): 4 ks x {1 ds_read + 2 MFMA}
__device__ __forceinline__ void compq(const uint4 (&d0)[4], const uint4 (&d1)[4],
                                      const char* wsrow, int q16, int xmask,
                                      int base, f32x4& acc0, f32x4& acc1)
{
#pragma unroll
    for (int j = 0; j < 4; ++j) {
        bf16x8 hv0, hv1;
        __builtin_memcpy(&hv0, &d0[j], 16);
        __builtin_memcpy(&hv1, &d1[j], 16);
        const int koff = ((base + j) * 64 + q16) ^ xmask;
        const bf16x8 av = *(const bf16x8*)(wsrow + koff);
        acc0 = __builtin_amdgcn_mfma_f32_16x16x32_bf16(av, hv0, acc0, 0, 0, 0);
        acc1 = __builtin_amdgcn_mfma_f32_16x16x32_bf16(av, hv1, acc1, 0, 0, 0);
    }
}

// ---- persistent LSTM scan, 256 blocks x 256 threads (ALL CUs) ----
// Rounds 7-11 showed the step time ~= in-CU serial compute (~5-7us on 32
// CUs) + exchange latency (~3us); 87% of the chip idled. New decomposition:
// block (x=bid&7, j=bid>>3) owns batch rows [32x,+32) x cells [16j,+16).
// Per-block work /8: 4 waves, 32 MFMAs + 2 cell-updates/lane/step. W_hh is
// replicated per batch-group (each j-slice staged by 8 blocks - one-time).
// Exchange protocol IDENTICAL to round 11 (proven): chain x has 32 producer
// flags (one per j), per-quarter waitg (quarter g needs j in [8g,+8)),
// sc0sc1 write-through h stores, 8B granularity (round-8 lesson) via
// shfl-pack of the 4 q-lanes' contiguous cells (new W permute: t<->q swap).
// Release: per-wave vmcnt drain -> s_barrier -> wave0 flag store.
__global__ __launch_bounds__(256)
void lstm_scan(const ushort_t* __restrict__ gx_p,   // [Tc*256][2048] bf16 (P-cols)
               const ushort_t* __restrict__ Whh_p,  // [2048][512] bf16 (scan permute)
               const float* __restrict__ b_hh,      // [2048] f32 gate-major
               const float* __restrict__ masks_c,   // [Tc*256]
               const ushort_t* h_init,              // [256][512] bf16
               float* __restrict__ c_state,         // [256][512] f32 in/out
               ushort_t* hid,                       // [Tc][256][512] bf16 out
               float* __restrict__ hT_f32,
               int Tc, int is_last,
               uint_t* __restrict__ bar)            // flags[8][32], 128B/chain
{
    __shared__ __align__(16) ushort_t Ws[64 * 512];   // 64 KiB, XOR-swizzled

    const int tid  = threadIdx.x;
    const int lane = tid & 63;
    const int w    = tid >> 6;            // wave 0..3 -> P-row tile w of slice
    const int q    = lane >> 4;           // 0..3
    const int s    = lane & 15;           // batch col within group
    const int x    = blockIdx.x & 7;      // batch group (XCD-heuristic spread)
    const int j    = blockIdx.x >> 3;     // cell slice 0..31
    const int xmask = (s & 7) << 4;       // LDS XOR swizzle
    const int q16  = q * 16;
    const int cell = j * 16 + w * 4 + q;  // lane's single cell

    // ---- W slice j -> LDS (swizzled); rows [j*64, +64), stride 1024 B ----
    for (int idx = tid; idx < 64 * 64; idx += 256) {
        const int row = idx >> 6;
        const int c16 = idx & 63;
        const uint4 v = *(const uint4*)(Whh_p + (size_t)(j * 64 + row) * CELL_D + c16 * 8);
        *(uint4*)((char*)Ws + row * 1024 + ((c16 * 16) ^ ((row & 7) << 4))) = v;
    }

    const int b0 = x * 32 + s;            // nfl=0 batch row
    const int b1 = b0 + 16;               // nfl=1

    // ---- per-lane state ----
    float creg0 = c_state[(size_t)b0 * CELL_D + cell];
    float creg1 = c_state[(size_t)b1 * CELL_D + cell];
    float bh[4];
#pragma unroll
    for (int r = 0; r < 4; ++r) bh[r] = b_hh[r * CELL_D + cell];

    // ---- gx/mask prefetch (gates of lane's cell for b0,b1) ----
    float mv0, mv1;
    uint2 gxv[2];
    auto prefetch_step = [&](int TL) {
        const ushort_t* g0 = gx_p + ((size_t)TL * BATCH + b0) * GATE_D + cell * 4;
        gxv[0] = *(const uint2*)g0;
        gxv[1] = *(const uint2*)(g0 + (size_t)16 * GATE_D);
        mv0 = masks_c[(size_t)TL * BATCH + b0];
        mv1 = masks_c[(size_t)TL * BATCH + b1];
    };

    const char* wsrow = (const char*)Ws + (w * 16 + s) * 1024;
    __syncthreads();                      // Ws staging complete

    for (int tl = 0; tl < Tc; ++tl) {
        const ushort_t* hp = (tl == 0) ? h_init
                                       : hid + (size_t)(tl - 1) * BATCH * CELL_D;
        const ushort_t* hr0 = hp + (size_t)b0 * CELL_D + q * 8;
        const ushort_t* hr1 = hp + (size_t)b1 * CELL_D + q * 8;

        // ---- per-quarter flag-group wait (flag >= tl: producer done t-1) ----
        uint64_t ready = 0;
        const uint_t tgt_in = (uint_t)tl;
        auto waitg = [&](int g) {
            const uint64_t need = 0xFFull << (g * 8);
            if ((ready & need) != need) {
                const uint_t* fp = bar + x * 32 + (lane & 31);
                for (;;) {
                    uint_t v;
                    asm volatile("global_load_dword %0, %1, off sc0 sc1\n\t"
                                 "s_waitcnt vmcnt(0)"
                                 : "=v"(v) : "v"(fp) : "memory");
                    ready = __ballot((int)(v >= tgt_in)) & 0xFFFFFFFFull;
                    if ((ready & need) == need) break;
                    __builtin_amdgcn_s_sleep(1);
                }
            }
            asm volatile("" ::: "memory");
        };

        f32x4 acc0 = (f32x4){0.f, 0.f, 0.f, 0.f};
        f32x4 acc1 = (f32x4){0.f, 0.f, 0.f, 0.f};

        // ---- pipelined: waitg(g) -> loadq(g) -> compq(g-1) ----
        uint4 A0[4], A1[4], B0[4], B1[4];
        if (tl) waitg(0);
        loadq(A0, A1, hr0, hr1, 0);
        prefetch_step(tl);
        if (tl) waitg(1);
        loadq(B0, B1, hr0, hr1, 4);
        compq(A0, A1, wsrow, q16, xmask, 0, acc0, acc1);
        if (tl) waitg(2);
        loadq(A0, A1, hr0, hr1, 8);
        compq(B0, B1, wsrow, q16, xmask, 4, acc0, acc1);
        if (tl) waitg(3);
        loadq(B0, B1, hr0, hr1, 12);
        compq(A0, A1, wsrow, q16, xmask, 8, acc0, acc1);
        compq(B0, B1, wsrow, q16, xmask, 12, acc0, acc1);

        // ---- cell update (mask post-MFMA; exact for keep in {0,1}) ----
        const float keep0 = (mv0 > 0.5f) ? 0.f : 1.f;
        const float keep1 = (mv1 > 0.5f) ? 0.f : 1.f;
        const ushort_t* gp0 = (const ushort_t*)&gxv[0];
        const ushort_t* gp1 = (const ushort_t*)&gxv[1];

        const float gi0 = fmaf(acc0[0], keep0, bf2f(gp0[0]) + bh[0]);
        const float gf0 = fmaf(acc0[1], keep0, bf2f(gp0[1]) + bh[1]);
        const float gg0 = fmaf(acc0[2], keep0, bf2f(gp0[2]) + bh[2]);
        const float go0 = fmaf(acc0[3], keep0, bf2f(gp0[3]) + bh[3]);
        const float cn0 = sigmoid_fast(gf0) * (creg0 * keep0)
                        + sigmoid_fast(gi0) * tanh_fast(gg0);
        const float hn0 = sigmoid_fast(go0) * tanh_fast(cn0);
        creg0 = cn0;

        const float gi1 = fmaf(acc1[0], keep1, bf2f(gp1[0]) + bh[0]);
        const float gf1 = fmaf(acc1[1], keep1, bf2f(gp1[1]) + bh[1]);
        const float gg1 = fmaf(acc1[2], keep1, bf2f(gp1[2]) + bh[2]);
        const float go1 = fmaf(acc1[3], keep1, bf2f(gp1[3]) + bh[3]);
        const float cn1 = sigmoid_fast(gf1) * (creg1 * keep1)
                        + sigmoid_fast(gi1) * tanh_fast(gg1);
        const float hn1 = sigmoid_fast(go1) * tanh_fast(cn1);
        creg1 = cn1;

        // ---- shfl-pack 4 q-lanes' contiguous cells -> 8B stores (q==0) ----
        const uint_t hv01 = (uint_t)f2bf(hn0) | ((uint_t)f2bf(hn1) << 16);
        const uint_t vA = (uint_t)__shfl((int)hv01, s + 16);
        const uint_t vB = (uint_t)__shfl((int)hv01, s + 32);
        const uint_t vC = (uint_t)__shfl((int)hv01, s + 48);
        if (q == 0) {
            u32x2 r0, r1;
            r0[0] = (hv01 & 0xFFFFu) | (vA << 16);
            r0[1] = (vB & 0xFFFFu) | (vC << 16);
            r1[0] = (hv01 >> 16) | (vA & 0xFFFF0000u);
            r1[1] = (vB >> 16) | (vC & 0xFFFF0000u);
            ushort_t* d0 = hid + (size_t)tl * BATCH * CELL_D
                         + (size_t)b0 * CELL_D + j * 16 + w * 4;
            ushort_t* d1 = hid + (size_t)tl * BATCH * CELL_D
                         + (size_t)b1 * CELL_D + j * 16 + w * 4;
            asm volatile("global_store_dwordx2 %0, %1, off sc0 sc1"
                         :: "v"(d0), "v"(r0) : "memory");
            asm volatile("global_store_dwordx2 %0, %1, off sc0 sc1"
                         :: "v"(d1), "v"(r1) : "memory");
        }
        if (is_last && tl == Tc - 1) {
            hT_f32[(size_t)b0 * CELL_D + cell] = hn0;
            hT_f32[(size_t)b1 * CELL_D + cell] = hn1;
        }

        if (tl == Tc - 1) break;   // last step: no release needed

        // ---- release: drain own stores, block barrier, wave0 sets flag ----
        asm volatile("s_waitcnt vmcnt(0)" ::: "memory");
        __builtin_amdgcn_s_barrier();
        if (tid == 0) {
            const uint_t tgt = (uint_t)(tl + 1);
            asm volatile("global_store_dword %0, %1, off sc0 sc1"
                         :: "v"(bar + x * 32 + j), "v"(tgt) : "memory");
        }
    }

    // ---- write back c ----
    c_state[(size_t)b0 * CELL_D + cell] = creg0;
    c_state[(size_t)b1 * CELL_D + cell] = creg1;
}

// means = tanh(h @ W_mean^T + b_mean); log_std broadcast. h is bf16.
__global__ __launch_bounds__(256)
void mean_head(const ushort_t* __restrict__ hiddens, const float* __restrict__ W_mean,
               const float* __restrict__ b_mean, const float* __restrict__ log_std,
               float* __restrict__ means_out, float* __restrict__ logstd_out)
{
    __shared__ float Wm[8][516];
    const int tid = threadIdx.x;
#pragma unroll
    for (int i = 0; i < 16; ++i) {
        int idx = i * 256 + tid;
        Wm[idx >> 9][idx & 511] = W_mean[idx];
    }
    __syncthreads();
    const int r = tid >> 3, a = tid & 7;
    const size_t m = (size_t)blockIdx.x * 32 + r;
    const ushort_t* hp = hiddens + m * CELL_D;
    float acc = 0.f;
#pragma unroll 2
    for (int k8 = 0; k8 < 64; ++k8) {
        const uint4 v = *(const uint4*)(hp + k8 * 8);
        const ushort_t* pv = (const ushort_t*)&v;
        const float* wv = &Wm[a][k8 * 8];
#pragma unroll
        for (int e = 0; e < 8; ++e) acc = fmaf(bf2f(pv[e]), wv[e], acc);
    }
    means_out[m * ACT_D + a]  = tanhf(acc + b_mean[a]);
    logstd_out[m * ACT_D + a] = log_std[a];
}

extern "C" void kernel_launch(void* const* d_in, const int* in_sizes, int n_in,
                              void* d_out, int out_size, void* d_ws, size_t ws_size,
                              hipStream_t stream)
{
    const float* xs     = (const float*)d_in[0];
    const float* h0     = (const float*)d_in[1];
    const float* c0     = (const float*)d_in[2];
    const float* masks  = (const float*)d_in[3];
    const float* W_in   = (const float*)d_in[4];
    const float* b_in   = (const float*)d_in[5];
    const float* W_ih   = (const float*)d_in[6];
    const float* b_ih   = (const float*)d_in[7];
    const float* W_hh   = (const float*)d_in[8];
    const float* b_hh   = (const float*)d_in[9];
    const float* W_mean = (const float*)d_in[10];
    const float* b_mean = (const float*)d_in[11];
    const float* lstd   = (const float*)d_in[12];

    const int M = T_STEPS * BATCH;
    const size_t stateB = (size_t)BATCH * CELL_D * sizeof(float);   // 512 KiB

    const size_t szWhh  = (size_t)GATE_D * CELL_D * 2;   // 2 MiB
    const size_t szWih  = (size_t)GATE_D * HID_D * 2;    // 4 MiB
    const size_t szWin  = (size_t)HID_D * OBS_D * 2;     // 128 KiB
    const size_t szH0b  = (size_t)BATCH * CELL_D * 2;    // 256 KiB
    const size_t szBih  = (size_t)GATE_D * 4;            // 8 KiB
    const size_t szBar  = 1024;
    const size_t fixed  = szWhh + szWih + szWin + szH0b + szBih + szBar + stateB;

    const size_t per_tc = (size_t)BATCH * GATE_D * 2     // gx_p bf16: 1 MiB
                        + (size_t)BATCH * CELL_D * 2     // hid bf16
                        + (size_t)BATCH * HID_D * 2      // E bf16
                        + (size_t)BATCH * OBS_D * 2;     // xs_b
    int Tc = T_STEPS;
    while (Tc > 2 && fixed + per_tc * (size_t)Tc > ws_size) Tc >>= 1;

    char* p = (char*)d_ws;
    ushort_t* Whh_p = (ushort_t*)p;              p += szWhh;
    ushort_t* Wih_p = (ushort_t*)p;              p += szWih;
    ushort_t* Win_b = (ushort_t*)p;              p += szWin;
    ushort_t* h0b   = (ushort_t*)p;              p += szH0b;
    float*    bihp  = (float*)p;                 p += szBih;
    uint_t*   bar   = (uint_t*)p;                p += szBar;
    float*    c_state = (float*)p;               p += stateB;
    ushort_t* gx_p  = (ushort_t*)p;              p += (size_t)Tc * BATCH * GATE_D * 2;
    ushort_t* hid   = (ushort_t*)p;              p += (size_t)Tc * BATCH * CELL_D * 2;
    ushort_t* E     = (ushort_t*)p;              p += (size_t)Tc * BATCH * HID_D * 2;
    ushort_t* xs_b  = (ushort_t*)p;

    float* means_out  = (float*)d_out;
    float* logstd_out = means_out + (size_t)M * ACT_D;
    float* hT_out     = logstd_out + (size_t)M * ACT_D;
    float* cT_out     = hT_out + (size_t)BATCH * CELL_D;

    // ---- one-shot converts / permutes / state init ----
    permute_whh_rows<<<GATE_D, 256, 0, stream>>>(W_hh, Whh_p, CELL_D);
    permute_gate_rows<<<GATE_D, 256, 0, stream>>>(W_ih, Wih_p, HID_D);
    cvt_f32_bf16<<<(HID_D * OBS_D) / 2048, 256, 0, stream>>>(W_in, Win_b);
    cvt_f32_bf16<<<(BATCH * CELL_D) / 2048, 256, 0, stream>>>(h0, h0b);
    permute_bias<<<GATE_D / 256, 256, 0, stream>>>(b_ih, bihp);
    hipMemcpyAsync(c_state, c0, stateB, hipMemcpyDeviceToDevice, stream);

    const int chunks = T_STEPS / Tc;
    for (int ci = 0; ci < chunks; ++ci) {
        const int t0 = ci * Tc;
        const int Mc = Tc * BATCH;

        cvt_f32_bf16<<<(Mc * OBS_D) / 2048, 256, 0, stream>>>(
            xs + (size_t)t0 * BATCH * OBS_D, xs_b);

        gemm_mfma_nt<1><<<dim3(HID_D / 128, Mc / 128), 256, 0, stream>>>(
            xs_b, Win_b, b_in, E, HID_D, OBS_D);

        gemm_mfma_nt<2><<<dim3(GATE_D / 128, Mc / 128), 256, 0, stream>>>(
            E, Wih_p, bihp, gx_p, GATE_D, HID_D);

        hipMemsetAsync(bar, 0, 1024, stream);
        const ushort_t* h_init = (ci == 0) ? h0b
                               : hid + (size_t)(Tc - 1) * BATCH * CELL_D;
        lstm_scan<<<SCAN_BLOCKS, 256, 0, stream>>>(
            gx_p, Whh_p, b_hh, masks + (size_t)t0 * BATCH, h_init,
            c_state, hid, hT_out, Tc, (ci == chunks - 1) ? 1 : 0, bar);

        mean_head<<<Mc / 32, 256, 0, stream>>>(
            hid, W_mean, b_mean, lstd,
            means_out + (size_t)t0 * BATCH * ACT_D,
            logstd_out + (size_t)t0 * BATCH * ACT_D);
    }

    hipMemcpyAsync(cT_out, c_state, stateB, hipMemcpyDeviceToDevice, stream);
}